// Round 9
// baseline (244.356 us; speedup 1.0000x reference)
//
#include <hip/hip_runtime.h>
#include <hip/hip_bf16.h>

// Problem constants
#define N_TOK   16384      // B*T
#define HDIM    2048       // H*d_h
#define NH      16
#define DH      128
#define NPAIRS  120
#define KCHUNKS 8
#define NKT     (N_TOK / 64)            // 256 k-tiles of 64 tokens
#define KT_PER_CHUNK (NKT / KCHUNKS)    // 32 panels per chunk
#define NCOLS   64                      // Σ_{g=0..7}(15-2g) block-columns
#define PANEL_BYTES 8192                // 128 c-rows x 64 tokens x 1B (fp8)

// Workspace layout (bytes) — total ~96.5 MB
#define SUM_OFF    0u
#define SUMSQ_OFF  8192u
#define PC_OFF     36864u                     // 8 kc-slabs x 120*128*128 f32 = 62,914,560 B
#define XT_OFF     62951424u                  // 2048*16384 fp8 = 33,554,432 B

typedef float f32x4  __attribute__((ext_vector_type(4)));
typedef float f32x16 __attribute__((ext_vector_type(16)));
typedef int   v8i    __attribute__((ext_vector_type(8)));
typedef int   v2i    __attribute__((ext_vector_type(2)));
typedef long long i64t;

// ---------------------------------------------------------------- fp8 e4m3 pack
#if __has_builtin(__builtin_amdgcn_cvt_pk_fp8_f32)
__device__ __forceinline__ unsigned pk4_fp8(float a, float b, float c, float d) {
    int w = __builtin_amdgcn_cvt_pk_fp8_f32(a, b, 0, false);   // bytes 0,1
    w = __builtin_amdgcn_cvt_pk_fp8_f32(c, d, w, true);        // bytes 2,3
    return (unsigned)w;
}
#else
__device__ __forceinline__ unsigned char f2e4m3_sw(float f) {
    unsigned u = __float_as_uint(f);
    unsigned s = (u >> 24) & 0x80u;
    unsigned a = u & 0x7fffffffu;
    if (a >= 0x43e00000u) return (unsigned char)(s | 0x7eu);   // clamp to 448
    if (a < 0x3c800000u) {                                     // |x| < 2^-6: subnormal
        float av = __uint_as_float(a);
        int q = (int)rintf(av * 512.0f);                       // units of 2^-9
        return (unsigned char)(s | (unsigned)q);               // q==8 -> 0x08 == 2^-6 normal
    }
    unsigned lsb = (a >> 20) & 1u;
    a += 0x7ffffu + lsb;                                       // RNE to 3 mantissa bits
    int e8 = (int)(a >> 23) - 120;                             // -127 + 7
    unsigned m = (a >> 20) & 7u;
    return (unsigned char)(s | ((unsigned)e8 << 3) | m);
}
__device__ __forceinline__ unsigned pk4_fp8(float a, float b, float c, float d) {
    return (unsigned)f2e4m3_sw(a) | ((unsigned)f2e4m3_sw(b) << 8) |
           ((unsigned)f2e4m3_sw(c) << 16) | ((unsigned)f2e4m3_sw(d) << 24);
}
#endif

// ---------------------------------------------------------------- pass 1: fused stats + panelized transpose + fp8
// Block = one 8 KB panel: head h, tokens n0..n0+63, all 128 head-dims.
// Rows with (c>>3)&1 store their two 8B halves SWAPPED, so the gram kernel's
// LDS read swizzle can include r-bit-3 -> structurally-minimal ds_read_b64 banking.
__global__ __launch_bounds__(256)
void stats_transpose_kernel(const float* __restrict__ X,
                            float* __restrict__ sum, float* __restrict__ sumsq,
                            unsigned char* __restrict__ Xt) {
    __shared__ float tile[64][129];               // stride 129
    __shared__ float sred[4][32][8];              // cross-wave stats partials
    const int h  = blockIdx.x;                    // 0..15
    const int by = blockIdx.y;                    // 0..255
    const int n0 = by * 64;
    const int tx = threadIdx.x;
    const int w  = tx >> 6, l = tx & 63;
    const int cq = tx & 31;                       // float4 index within 128-col slice
    const int rq0 = tx >> 5;                      // 0..7

    float4 s  = make_float4(0.f, 0.f, 0.f, 0.f);
    float4 ss = make_float4(0.f, 0.f, 0.f, 0.f);
    #pragma unroll
    for (int it = 0; it < 8; ++it) {
        int r = it * 8 + rq0;
        float4 x = *(const float4*)(X + (size_t)(n0 + r) * HDIM + h * DH + cq * 4);
        s.x += x.x; s.y += x.y; s.z += x.z; s.w += x.w;
        ss.x += x.x * x.x; ss.y += x.y * x.y; ss.z += x.z * x.z; ss.w += x.w * x.w;
        tile[r][cq * 4 + 0] = x.x; tile[r][cq * 4 + 1] = x.y;
        tile[r][cq * 4 + 2] = x.z; tile[r][cq * 4 + 3] = x.w;
    }
    s.x += __shfl_down(s.x, 32);  s.y += __shfl_down(s.y, 32);
    s.z += __shfl_down(s.z, 32);  s.w += __shfl_down(s.w, 32);
    ss.x += __shfl_down(ss.x, 32); ss.y += __shfl_down(ss.y, 32);
    ss.z += __shfl_down(ss.z, 32); ss.w += __shfl_down(ss.w, 32);
    if (l < 32) {
        sred[w][l][0] = s.x;  sred[w][l][1] = s.y;
        sred[w][l][2] = s.z;  sred[w][l][3] = s.w;
        sred[w][l][4] = ss.x; sred[w][l][5] = ss.y;
        sred[w][l][6] = ss.z; sred[w][l][7] = ss.w;
    }
    __syncthreads();
    if (tx < 32) {                                // wave 0 finishes stats
        float a0 = 0.f, a1 = 0.f, a2 = 0.f, a3 = 0.f;
        float b0 = 0.f, b1 = 0.f, b2 = 0.f, b3 = 0.f;
        #pragma unroll
        for (int w2 = 0; w2 < 4; ++w2) {
            a0 += sred[w2][tx][0]; a1 += sred[w2][tx][1];
            a2 += sred[w2][tx][2]; a3 += sred[w2][tx][3];
            b0 += sred[w2][tx][4]; b1 += sred[w2][tx][5];
            b2 += sred[w2][tx][6]; b3 += sred[w2][tx][7];
        }
        int c = h * DH + tx * 4;
        atomicAdd(&sum[c + 0], a0);  atomicAdd(&sum[c + 1], a1);
        atomicAdd(&sum[c + 2], a2);  atomicAdd(&sum[c + 3], a3);
        atomicAdd(&sumsq[c + 0], b0); atomicAdd(&sumsq[c + 1], b1);
        atomicAdd(&sumsq[c + 2], b2); atomicAdd(&sumsq[c + 3], b3);
    }
    // transpose write: 512 16B-chunks (one panel), contiguous per wave-instruction
    unsigned char* panel = Xt + ((size_t)h * NKT + by) * PANEL_BYTES;
    #pragma unroll
    for (int it = 0; it < 2; ++it) {
        int q = it * 256 + tx;
        int c = q >> 2, o = q & 3;                // chunk = (dim c, tokens 16o..16o+15)
        uint4 pk;
        pk.x = pk4_fp8(tile[o*16+ 0][c], tile[o*16+ 1][c], tile[o*16+ 2][c], tile[o*16+ 3][c]);
        pk.y = pk4_fp8(tile[o*16+ 4][c], tile[o*16+ 5][c], tile[o*16+ 6][c], tile[o*16+ 7][c]);
        pk.z = pk4_fp8(tile[o*16+ 8][c], tile[o*16+ 9][c], tile[o*16+10][c], tile[o*16+11][c]);
        pk.w = pk4_fp8(tile[o*16+12][c], tile[o*16+13][c], tile[o*16+14][c], tile[o*16+15][c]);
        // r-bit-3 half-swap: bakes the missing swizzle bit into the data so the
        // consumer's bank index depends on all 4 low row bits.
        uint4 outv = ((c >> 3) & 1) ? make_uint4(pk.z, pk.w, pk.x, pk.y) : pk;
        *(uint4*)(panel + c * 64 + o * 16) = outv;
    }
}

// ---------------------------------------------------------------- pass 3: grouped Gram via MX-fp8 MFMA (32x32x64)
// LDS-balance restructure: block = (head-group g={2g,2g+1}) x (head j>2g),
// tile 256x128 = TWO pair-tiles sharing the B panel. 8 waves, 4x2 grid,
// wave tile 64x64: 8 KB LDS-read for 4 MFMA = 65.5 FLOP/B > 59.6 balance
// -> MFMA-bound (previous 64x32 tiles were 42.7 FLOP/B = LDS-bound).
// 64 cols cover all 120 pairs exactly once (8 diagonal cols half-idle).
// Grid 512 = 64 cols x 8 kc; kc = bid&7 pins kc->XCD: per-XCD slice = 4 MB = L2.
// 2-slot dbuf (48 KB -> 2 blocks/CU = 4 waves/SIMD); prefetch issued before the
// ~1300-cyc compute phase fully covers load latency, so the vmcnt(0) is free.
__device__ __forceinline__ void gload16(const void* gsrc, void* ldst) {
    __builtin_amdgcn_global_load_lds(
        (const __attribute__((address_space(1))) unsigned int*)gsrc,
        (__attribute__((address_space(3))) unsigned int*)ldst,
        16, 0, 0);
}

// Register-resident gather: 4x ds_read_b64 -> v8i via constant-index inserts.
__device__ __forceinline__ v8i gather_frag(const unsigned char* rp,
                                           int o0, int o1, int o2, int o3) {
    v2i x0 = *(const v2i*)(rp + o0);
    v2i x1 = *(const v2i*)(rp + o1);
    v2i x2 = *(const v2i*)(rp + o2);
    v2i x3 = *(const v2i*)(rp + o3);
    v8i r;
    r[0] = x0[0]; r[1] = x0[1];
    r[2] = x1[0]; r[3] = x1[1];
    r[4] = x2[0]; r[5] = x2[1];
    r[6] = x3[0]; r[7] = x3[1];
    return r;
}

__global__ __launch_bounds__(512, 4)
void gram_kernel(const unsigned char* __restrict__ Xt, float* __restrict__ pairP) {
    const int bid = blockIdx.x;                   // 0..511
    const int kc  = bid & 7;                      // XCD-pinned K-chunk
    const int col = bid >> 3;                     // 0..63
    int g = 0, rem = col;
    while (rem >= 15 - 2 * g) { rem -= 15 - 2 * g; ++g; }
    const int j = 2 * g + 1 + rem;                // B head (j > 2g)

    // 2 slots x [A0|A1|B] = 48 KB -> 2 blocks/CU
    __shared__ alignas(16) unsigned char lds[2 * 3 * PANEL_BYTES];

    const int tx = threadIdx.x;
    const int w  = tx >> 6, l = tx & 63;
    const int wm = w >> 1, wn = w & 1;            // 4x2 wave grid; wave tile 64x64
    const int l31 = l & 31, half = l >> 5;

    // Staging source swizzle (16B chunk level): cc = cl ^ ((r>>1)&3).
    unsigned int goff;
    {
        int r0 = tx >> 2, cl0 = tx & 3;
        goff = (unsigned int)(r0 * 64 + (cl0 ^ ((r0 >> 1) & 3)) * 16);
    }
    const int lo = w * 1024;                      // wave-uniform LDS base
    const char* P0 = (const char*)Xt + ((size_t)(2 * g)     * NKT + (size_t)kc * KT_PER_CHUNK) * PANEL_BYTES;
    const char* P1 = (const char*)Xt + ((size_t)(2 * g + 1) * NKT + (size_t)kc * KT_PER_CHUNK) * PANEL_BYTES;
    const char* PB = (const char*)Xt + ((size_t)j           * NKT + (size_t)kc * KT_PER_CHUNK) * PANEL_BYTES;

    // stage one 3-panel step (24 KB): 3 gload16 per thread
    auto STAGE = [&](int s, char* base) {
        gload16(P0 + (size_t)s * PANEL_BYTES + goff, base + lo);
        gload16(P1 + (size_t)s * PANEL_BYTES + goff, base + PANEL_BYTES + lo);
        gload16(PB + (size_t)s * PANEL_BYTES + goff, base + 2 * PANEL_BYTES + lo);
    };

    f32x16 acc00, acc01, acc10, acc11;            // [mi][ni], named (no dyn idx)
    #pragma unroll
    for (int e = 0; e < 16; ++e) { acc00[e] = 0.f; acc01[e] = 0.f; acc10[e] = 0.f; acc11[e] = 0.f; }

    // Row-dependent unit swizzle (r == l31 mod 32 within a fragment)
    const int usw = (l31 & 6) | ((l31 >> 3) & 1);
    const int puo0 = (((half * 4) + 0) ^ usw) * 8;
    const int puo1 = (((half * 4) + 1) ^ usw) * 8;
    const int puo2 = (((half * 4) + 2) ^ usw) * 8;
    const int puo3 = (((half * 4) + 3) ^ usw) * 8;
    // A: head panel (wm>>1), rows (wm&1)*64 + mi*32; B: rows wn*64 + ni*32
    const int offA0 = (wm >> 1) * PANEL_BYTES + ((wm & 1) * 64 +  0 + l31) * 64;
    const int offA1 = (wm >> 1) * PANEL_BYTES + ((wm & 1) * 64 + 32 + l31) * 64;
    const int offB0 = 2 * PANEL_BYTES + (wn * 64 +  0 + l31) * 64;
    const int offB1 = 2 * PANEL_BYTES + (wn * 64 + 32 + l31) * 64;

    // ---- prologue
    STAGE(0, (char*)lds);
    asm volatile("s_waitcnt vmcnt(0)\n\ts_barrier" ::: "memory");

    int cur = 0;
    for (int s = 0; s < KT_PER_CHUNK; ++s) {
        if (s + 1 < KT_PER_CHUNK)
            STAGE(s + 1, (char*)lds + (cur ^ 1) * (3 * PANEL_BYTES));

        const unsigned char* base = lds + cur * (3 * PANEL_BYTES);
        __builtin_amdgcn_s_setprio(1);
        v8i a0 = gather_frag(base + offA0, puo0, puo1, puo2, puo3);
        v8i a1 = gather_frag(base + offA1, puo0, puo1, puo2, puo3);
        {
            v8i b0 = gather_frag(base + offB0, puo0, puo1, puo2, puo3);
            acc00 = __builtin_amdgcn_mfma_scale_f32_32x32x64_f8f6f4(
                a0, b0, acc00, 0, 0, 0, 0x7F7F7F7F, 0, 0x7F7F7F7F);
            acc10 = __builtin_amdgcn_mfma_scale_f32_32x32x64_f8f6f4(
                a1, b0, acc10, 0, 0, 0, 0x7F7F7F7F, 0, 0x7F7F7F7F);
        }
        {
            v8i b1 = gather_frag(base + offB1, puo0, puo1, puo2, puo3);
            acc01 = __builtin_amdgcn_mfma_scale_f32_32x32x64_f8f6f4(
                a0, b1, acc01, 0, 0, 0, 0x7F7F7F7F, 0, 0x7F7F7F7F);
            acc11 = __builtin_amdgcn_mfma_scale_f32_32x32x64_f8f6f4(
                a1, b1, acc11, 0, 0, 0, 0x7F7F7F7F, 0, 0x7F7F7F7F);
        }
        __builtin_amdgcn_s_setprio(0);

        if (s + 1 < KT_PER_CHUNK)
            asm volatile("s_waitcnt vmcnt(0) lgkmcnt(0)\n\ts_barrier" ::: "memory");
        cur ^= 1;
    }

    // Epilogue: this wave's pair-tile is head hi = 2g + (wm>>1) vs head j.
    // Valid iff hi < j (hi == j only on the 8 diagonal cols, upper A1 waves idle).
    const int hi = 2 * g + (wm >> 1);
    if (hi < j) {
        const int p = hi * 15 - (hi * (hi - 1)) / 2 + (j - hi - 1);
        float* pc = pairP + ((size_t)kc * NPAIRS + (size_t)p) * (DH * DH);
        #pragma unroll
        for (int e = 0; e < 16; ++e) {
            int rl  = (e & 3) + 8 * (e >> 2) + 4 * half;   // 32x32 C/D row map
            int row = (wm & 1) * 64 + rl;
            int c0  = wn * 64 + l31;
            pc[row * DH + c0]             = acc00[e];
            pc[row * DH + c0 + 32]        = acc01[e];
            pc[(row + 32) * DH + c0]      = acc10[e];
            pc[(row + 32) * DH + c0 + 32] = acc11[e];
        }
    }
}

// ---------------------------------------------------------------- pass 4: per-pair loss + final accumulate
// Sums the 8 kc-slabs (float4-vectorized), normalizes, reduces.
__global__ void pair_reduce_kernel(const float* __restrict__ pairP, const float* __restrict__ G,
                                   const float* __restrict__ sum, const float* __restrict__ sumsq,
                                   float* __restrict__ out) {
    int p = blockIdx.x;
    int i = 0, rem = p;
    while (rem >= NH - 1 - i) { rem -= NH - 1 - i; ++i; }
    int j = i + 1 + rem;
    __shared__ float smui[DH], smuj[DH], sri[DH], srj[DH];
    {
        int t = threadIdx.x;
        int head = (t < DH) ? i : j;
        int d = t & (DH - 1);
        int c = head * DH + d;
        float m = sum[c] * (1.f / (float)N_TOK);
        float var = (sumsq[c] - (float)N_TOK * m * m) * (1.f / (float)(N_TOK - 1));
        var = fmaxf(var, 0.f);
        float r = 1.f / (sqrtf(var) + 1e-8f);
        if (t < DH) { smui[d] = m; sri[d] = r; }
        else        { smuj[d] = m; srj[d] = r; }
    }
    __syncthreads();
    const float invN = 1.f / (float)N_TOK;
    const size_t SLAB = (size_t)NPAIRS * DH * DH;     // floats per kc slab
    const float* base = pairP + (size_t)p * (DH * DH);
    float s = 0.f;
    for (int q = threadIdx.x; q < (DH * DH) / 4; q += 256) {
        float4 v = ((const float4*)base)[q];
        #pragma unroll
        for (int kc = 1; kc < KCHUNKS; ++kc) {
            float4 t = ((const float4*)(base + kc * SLAB))[q];
            v.x += t.x; v.y += t.y; v.z += t.z; v.w += t.w;
        }
        int d = q >> 5;                // 32 float4 per 128-col row
        int e0 = (q & 31) * 4;
        float md = smui[d], rd = sri[d];
        float cn, df;
        cn = (v.x * invN - md * smuj[e0 + 0]) * rd * srj[e0 + 0];
        df = cn - ((d == e0 + 0) ? 1.f : 0.f); s += df * df;
        cn = (v.y * invN - md * smuj[e0 + 1]) * rd * srj[e0 + 1];
        df = cn - ((d == e0 + 1) ? 1.f : 0.f); s += df * df;
        cn = (v.z * invN - md * smuj[e0 + 2]) * rd * srj[e0 + 2];
        df = cn - ((d == e0 + 2) ? 1.f : 0.f); s += df * df;
        cn = (v.w * invN - md * smuj[e0 + 3]) * rd * srj[e0 + 3];
        df = cn - ((d == e0 + 3) ? 1.f : 0.f); s += df * df;
    }
    for (int o = 32; o; o >>= 1) s += __shfl_down(s, o);
    __shared__ float red[4];
    if ((threadIdx.x & 63) == 0) red[threadIdx.x >> 6] = s;
    __syncthreads();
    if (threadIdx.x == 0) {
        float t = red[0] + red[1] + red[2] + red[3];
        float x = -15.99f * (G[i * NH + j] - 0.0f);
        float sp = (x > 20.f) ? x : log1pf(expf(x));
        float wgt = 0.929f + (1.f - 0.929f) * sp;
        atomicAdd(out, wgt * t * (1.f / (float)NPAIRS));
    }
}

// ---------------------------------------------------------------- launcher
extern "C" void kernel_launch(void* const* d_in, const int* in_sizes, int n_in,
                              void* d_out, int out_size, void* d_ws, size_t ws_size,
                              hipStream_t stream) {
    const float* X = (const float*)d_in[0];
    const float* G = (const float*)d_in[1];
    float* out = (float*)d_out;
    char* ws = (char*)d_ws;

    float*         sum   = (float*)(ws + SUM_OFF);
    float*         sumsq = (float*)(ws + SUMSQ_OFF);
    float*         pairP = (float*)(ws + PC_OFF);
    unsigned char* Xt    = (unsigned char*)(ws + XT_OFF);

    hipMemsetAsync(ws + SUM_OFF, 0, 16384, stream);                     // sum+sumsq
    hipMemsetAsync(d_out, 0, 4, stream);

    stats_transpose_kernel<<<dim3(16, 256), 256, 0, stream>>>(X, sum, sumsq, Xt);
    gram_kernel<<<NCOLS * KCHUNKS, 512, 0, stream>>>(Xt, pairP);
    pair_reduce_kernel<<<NPAIRS, 256, 0, stream>>>(pairP, G, sum, sumsq, out);
}

// Round 10
// 241.747 us; speedup vs baseline: 1.0108x; 1.0108x over previous
//
#include <hip/hip_runtime.h>
#include <hip/hip_bf16.h>

// Problem constants
#define N_TOK   16384      // B*T
#define HDIM    2048       // H*d_h
#define NH      16
#define DH      128
#define NPAIRS  120
#define KCHUNKS 4
#define NKT     (N_TOK / 64)            // 256 k-tiles of 64 tokens
#define KT_PER_CHUNK (NKT / KCHUNKS)    // 64 (64-token panels per chunk)
#define SKT     KT_PER_CHUNK            // panel-steps per gram block
#define PANEL_BYTES 8192                // 128 c-rows x 64 tokens x 1B (fp8)

// Workspace layout (bytes) — total ~65 MB
#define SUM_OFF    0u
#define SUMSQ_OFF  8192u
#define PC_OFF     36864u                     // 4 kc-slabs x 120*128*128 f32 = 31,457,280 B
#define XT_OFF     31494144u                  // 2048*16384 fp8 = 33,554,432 B

typedef float f32x4  __attribute__((ext_vector_type(4)));
typedef float f32x16 __attribute__((ext_vector_type(16)));
typedef int   v8i    __attribute__((ext_vector_type(8)));
typedef int   v2i    __attribute__((ext_vector_type(2)));
typedef long long i64t;

// ---------------------------------------------------------------- fp8 e4m3 pack
#if __has_builtin(__builtin_amdgcn_cvt_pk_fp8_f32)
__device__ __forceinline__ unsigned pk4_fp8(float a, float b, float c, float d) {
    int w = __builtin_amdgcn_cvt_pk_fp8_f32(a, b, 0, false);   // bytes 0,1
    w = __builtin_amdgcn_cvt_pk_fp8_f32(c, d, w, true);        // bytes 2,3
    return (unsigned)w;
}
#else
__device__ __forceinline__ unsigned char f2e4m3_sw(float f) {
    unsigned u = __float_as_uint(f);
    unsigned s = (u >> 24) & 0x80u;
    unsigned a = u & 0x7fffffffu;
    if (a >= 0x43e00000u) return (unsigned char)(s | 0x7eu);   // clamp to 448
    if (a < 0x3c800000u) {                                     // |x| < 2^-6: subnormal
        float av = __uint_as_float(a);
        int q = (int)rintf(av * 512.0f);                       // units of 2^-9
        return (unsigned char)(s | (unsigned)q);               // q==8 -> 0x08 == 2^-6 normal
    }
    unsigned lsb = (a >> 20) & 1u;
    a += 0x7ffffu + lsb;                                       // RNE to 3 mantissa bits
    int e8 = (int)(a >> 23) - 120;                             // -127 + 7
    unsigned m = (a >> 20) & 7u;
    return (unsigned char)(s | ((unsigned)e8 << 3) | m);
}
__device__ __forceinline__ unsigned pk4_fp8(float a, float b, float c, float d) {
    return (unsigned)f2e4m3_sw(a) | ((unsigned)f2e4m3_sw(b) << 8) |
           ((unsigned)f2e4m3_sw(c) << 16) | ((unsigned)f2e4m3_sw(d) << 24);
}
#endif

// ---------------------------------------------------------------- pass 1: fused stats + panelized transpose + fp8
// Block = one 8 KB panel: head h, tokens n0..n0+63, all 128 head-dims.
// Rows with (c>>3)&1 store their two 8B halves SWAPPED, so the gram kernel's
// LDS read swizzle can include r-bit-3 -> structurally-minimal ds_read_b64 banking.
__global__ __launch_bounds__(256)
void stats_transpose_kernel(const float* __restrict__ X,
                            float* __restrict__ sum, float* __restrict__ sumsq,
                            unsigned char* __restrict__ Xt) {
    __shared__ float tile[64][129];               // stride 129
    __shared__ float sred[4][32][8];              // cross-wave stats partials
    const int h  = blockIdx.x;                    // 0..15
    const int by = blockIdx.y;                    // 0..255
    const int n0 = by * 64;
    const int tx = threadIdx.x;
    const int w  = tx >> 6, l = tx & 63;
    const int cq = tx & 31;                       // float4 index within 128-col slice
    const int rq0 = tx >> 5;                      // 0..7

    float4 s  = make_float4(0.f, 0.f, 0.f, 0.f);
    float4 ss = make_float4(0.f, 0.f, 0.f, 0.f);
    #pragma unroll
    for (int it = 0; it < 8; ++it) {
        int r = it * 8 + rq0;
        float4 x = *(const float4*)(X + (size_t)(n0 + r) * HDIM + h * DH + cq * 4);
        s.x += x.x; s.y += x.y; s.z += x.z; s.w += x.w;
        ss.x += x.x * x.x; ss.y += x.y * x.y; ss.z += x.z * x.z; ss.w += x.w * x.w;
        tile[r][cq * 4 + 0] = x.x; tile[r][cq * 4 + 1] = x.y;
        tile[r][cq * 4 + 2] = x.z; tile[r][cq * 4 + 3] = x.w;
    }
    s.x += __shfl_down(s.x, 32);  s.y += __shfl_down(s.y, 32);
    s.z += __shfl_down(s.z, 32);  s.w += __shfl_down(s.w, 32);
    ss.x += __shfl_down(ss.x, 32); ss.y += __shfl_down(ss.y, 32);
    ss.z += __shfl_down(ss.z, 32); ss.w += __shfl_down(ss.w, 32);
    if (l < 32) {
        sred[w][l][0] = s.x;  sred[w][l][1] = s.y;
        sred[w][l][2] = s.z;  sred[w][l][3] = s.w;
        sred[w][l][4] = ss.x; sred[w][l][5] = ss.y;
        sred[w][l][6] = ss.z; sred[w][l][7] = ss.w;
    }
    __syncthreads();
    if (tx < 32) {                                // wave 0 finishes stats
        float a0 = 0.f, a1 = 0.f, a2 = 0.f, a3 = 0.f;
        float b0 = 0.f, b1 = 0.f, b2 = 0.f, b3 = 0.f;
        #pragma unroll
        for (int w2 = 0; w2 < 4; ++w2) {
            a0 += sred[w2][tx][0]; a1 += sred[w2][tx][1];
            a2 += sred[w2][tx][2]; a3 += sred[w2][tx][3];
            b0 += sred[w2][tx][4]; b1 += sred[w2][tx][5];
            b2 += sred[w2][tx][6]; b3 += sred[w2][tx][7];
        }
        int c = h * DH + tx * 4;
        atomicAdd(&sum[c + 0], a0);  atomicAdd(&sum[c + 1], a1);
        atomicAdd(&sum[c + 2], a2);  atomicAdd(&sum[c + 3], a3);
        atomicAdd(&sumsq[c + 0], b0); atomicAdd(&sumsq[c + 1], b1);
        atomicAdd(&sumsq[c + 2], b2); atomicAdd(&sumsq[c + 3], b3);
    }
    // transpose write: 512 16B-chunks (one panel), contiguous per wave-instruction
    unsigned char* panel = Xt + ((size_t)h * NKT + by) * PANEL_BYTES;
    #pragma unroll
    for (int it = 0; it < 2; ++it) {
        int q = it * 256 + tx;
        int c = q >> 2, o = q & 3;                // chunk = (dim c, tokens 16o..16o+15)
        uint4 pk;
        pk.x = pk4_fp8(tile[o*16+ 0][c], tile[o*16+ 1][c], tile[o*16+ 2][c], tile[o*16+ 3][c]);
        pk.y = pk4_fp8(tile[o*16+ 4][c], tile[o*16+ 5][c], tile[o*16+ 6][c], tile[o*16+ 7][c]);
        pk.z = pk4_fp8(tile[o*16+ 8][c], tile[o*16+ 9][c], tile[o*16+10][c], tile[o*16+11][c]);
        pk.w = pk4_fp8(tile[o*16+12][c], tile[o*16+13][c], tile[o*16+14][c], tile[o*16+15][c]);
        // r-bit-3 half-swap: bakes the missing swizzle bit into the data so the
        // consumer's bank index depends on all 4 low row bits.
        uint4 outv = ((c >> 3) & 1) ? make_uint4(pk.z, pk.w, pk.x, pk.y) : pk;
        *(uint4*)(panel + c * 64 + o * 16) = outv;
    }
}

// ---------------------------------------------------------------- pass 3: pairwise raw Gram via MX-fp8 MFMA (32x32x64)
// Round-8 best config (239.9 µs), restored verbatim. Counted-vmcnt ring:
// 4-slot LDS ring (64 KB -> 2 blocks/CU, 4 waves/SIMD), prefetch depth 3,
// uniform s_waitcnt vmcnt(4) (never 0 in the loop), ONE barrier per panel-step.
// 8 waves in 2x4 grid; per wave 64x32 out = 2 x mfma_scale 32x32x64 per panel.
__device__ __forceinline__ void gload16(const void* gsrc, void* ldst) {
    __builtin_amdgcn_global_load_lds(
        (const __attribute__((address_space(1))) unsigned int*)gsrc,
        (__attribute__((address_space(3))) unsigned int*)ldst,
        16, 0, 0);
}

// Register-resident gather: 4x ds_read_b64 -> v8i via constant-index inserts.
__device__ __forceinline__ v8i gather_frag(const unsigned char* rp,
                                           int o0, int o1, int o2, int o3) {
    v2i x0 = *(const v2i*)(rp + o0);
    v2i x1 = *(const v2i*)(rp + o1);
    v2i x2 = *(const v2i*)(rp + o2);
    v2i x3 = *(const v2i*)(rp + o3);
    v8i r;
    r[0] = x0[0]; r[1] = x0[1];
    r[2] = x1[0]; r[3] = x1[1];
    r[4] = x2[0]; r[5] = x2[1];
    r[6] = x3[0]; r[7] = x3[1];
    return r;
}

__global__ __launch_bounds__(512, 2)
void gram_kernel(const unsigned char* __restrict__ Xt, float* __restrict__ pairP) {
    const int kc = blockIdx.x;                    // K-chunk 0..3
    const int p  = blockIdx.y;                    // pair 0..119
    int i = 0, rem = p;
    while (rem >= NH - 1 - i) { rem -= NH - 1 - i; ++i; }
    const int j = i + 1 + rem;

    // 4-slot ring: slot = [A 8KB | B 8KB] = 16 KB; 64 KB total
    __shared__ alignas(16) unsigned char lds[4 * 2 * PANEL_BYTES];

    const int tx = threadIdx.x;
    const int w  = tx >> 6, l = tx & 63;
    const int wm = w >> 2, wn = w & 3;            // 2x4 wave grid; wave out 64x32
    const int l31 = l & 31, half = l >> 5;

    // Staging source swizzle (16B chunk level): cc = cl ^ ((r>>1)&3).
    unsigned int goff;
    {
        int r0 = tx >> 2, cl0 = tx & 3;
        goff = (unsigned int)(r0 * 64 + (cl0 ^ ((r0 >> 1) & 3)) * 16);
    }
    const int lo = w * 1024;                      // wave-uniform LDS base
    const char* Abase = (const char*)Xt + ((size_t)i * NKT + (size_t)kc * KT_PER_CHUNK) * PANEL_BYTES;
    const char* Bbase = (const char*)Xt + ((size_t)j * NKT + (size_t)kc * KT_PER_CHUNK) * PANEL_BYTES;

    // stage one panel-pair (16 KB): 2 gload16 per thread
    auto STAGE = [&](int s, int slot) {
        const char* pa = Abase + (size_t)s * PANEL_BYTES;
        const char* pb = Bbase + (size_t)s * PANEL_BYTES;
        char* base = (char*)lds + slot * (2 * PANEL_BYTES);
        gload16(pa + goff, base + lo);
        gload16(pb + goff, base + PANEL_BYTES + lo);
    };

    f32x16 acc0, acc1;
    #pragma unroll
    for (int e = 0; e < 16; ++e) { acc0[e] = 0.f; acc1[e] = 0.f; }

    // Row-dependent unit swizzle (r == l31 mod 32 within a fragment)
    const int usw = (l31 & 6) | ((l31 >> 3) & 1);
    const int puo0 = (((half * 4) + 0) ^ usw) * 8;  // lane's 4 k-units (k = half*32..+31)
    const int puo1 = (((half * 4) + 1) ^ usw) * 8;
    const int puo2 = (((half * 4) + 2) ^ usw) * 8;
    const int puo3 = (((half * 4) + 3) ^ usw) * 8;
    const int offA0 = (wm * 64 +  0 + l31) * 64;            // mi=0 row-tile
    const int offA1 = (wm * 64 + 32 + l31) * 64;            // mi=1 row-tile
    const int offB  = PANEL_BYTES + (wn * 32 + l31) * 64;   // col-tile

    // ---- prologue: stage panels 0,1,2 into slots 0,1,2 (6 loads/thread in flight)
    STAGE(0, 0); STAGE(1, 1); STAGE(2, 2);
    asm volatile("s_waitcnt vmcnt(4)\n\ts_barrier" ::: "memory");   // slot0 ready

    for (int s = 0; s < SKT; ++s) {
        // issue prefetch (depth 3). Overwrites slot (s-1)&3 — its readers drained
        // at end of iter s-1 (lgkmcnt(0)+barrier).
        STAGE((s + 3) & (SKT - 1), (s + 3) & 3);

        const unsigned char* sb = lds + (s & 3) * (2 * PANEL_BYTES);
        __builtin_amdgcn_s_setprio(1);
        v8i a0 = gather_frag(sb + offA0, puo0, puo1, puo2, puo3);
        v8i a1 = gather_frag(sb + offA1, puo0, puo1, puo2, puo3);
        v8i b  = gather_frag(sb + offB,  puo0, puo1, puo2, puo3);
        acc0 = __builtin_amdgcn_mfma_scale_f32_32x32x64_f8f6f4(
            a0, b, acc0, 0, 0, 0, 0x7F7F7F7F, 0, 0x7F7F7F7F);
        acc1 = __builtin_amdgcn_mfma_scale_f32_32x32x64_f8f6f4(
            a1, b, acc1, 0, 0, 0, 0x7F7F7F7F, 0, 0x7F7F7F7F);
        __builtin_amdgcn_s_setprio(0);

        // counted wait: 6 loads in flight (s+1,s+2,s+3); wait oldest 2 -> slot for
        // s+1 is ready. Never vmcnt(0) in the loop. lgkm(0): our reads retired.
        asm volatile("s_waitcnt vmcnt(4) lgkmcnt(0)\n\ts_barrier" ::: "memory");
    }
    asm volatile("s_waitcnt vmcnt(0)" ::: "memory");  // drain wraparound stages

    // Epilogue: plain stores into this kc's slab. 32x32 C/D layout:
    // col = l31, row_local = (e&3) + 8*(e>>2) + 4*half  (shape-determined).
    float* pc = pairP + ((size_t)kc * NPAIRS + (size_t)p) * (DH * DH);
    #pragma unroll
    for (int e = 0; e < 16; ++e) {
        int rl = (e & 3) + 8 * (e >> 2) + 4 * half;
        int row = wm * 64 + rl;
        int col = wn * 32 + l31;
        pc[row * DH + col]        = acc0[e];
        pc[(row + 32) * DH + col] = acc1[e];
    }
}

// ---------------------------------------------------------------- pass 4: per-pair loss + final accumulate
// Sums the kc-slabs (float4-vectorized), normalizes, reduces.
// 512 threads (was 256): doubles TLP on the latency-chained slab loads.
__global__ __launch_bounds__(512)
void pair_reduce_kernel(const float* __restrict__ pairP, const float* __restrict__ G,
                        const float* __restrict__ sum, const float* __restrict__ sumsq,
                        float* __restrict__ out) {
    int p = blockIdx.x;
    int i = 0, rem = p;
    while (rem >= NH - 1 - i) { rem -= NH - 1 - i; ++i; }
    int j = i + 1 + rem;
    __shared__ float smui[DH], smuj[DH], sri[DH], srj[DH];
    {
        int t = threadIdx.x;
        int head = (t < DH) ? i : j;
        int d = t & (DH - 1);
        int c = head * DH + d;
        float m = sum[c] * (1.f / (float)N_TOK);
        float var = (sumsq[c] - (float)N_TOK * m * m) * (1.f / (float)(N_TOK - 1));
        var = fmaxf(var, 0.f);
        float r = 1.f / (sqrtf(var) + 1e-8f);
        // t in [256,512) recomputes head j values — redundant but identical.
        if (t < DH) { smui[d] = m; sri[d] = r; }
        else        { smuj[d] = m; srj[d] = r; }
    }
    __syncthreads();
    const float invN = 1.f / (float)N_TOK;
    const size_t SLAB = (size_t)NPAIRS * DH * DH;     // floats per kc slab
    const float* base = pairP + (size_t)p * (DH * DH);
    float s = 0.f;
    for (int q = threadIdx.x; q < (DH * DH) / 4; q += 512) {
        float4 v = ((const float4*)base)[q];
        #pragma unroll
        for (int kc = 1; kc < KCHUNKS; ++kc) {
            float4 t = ((const float4*)(base + kc * SLAB))[q];
            v.x += t.x; v.y += t.y; v.z += t.z; v.w += t.w;
        }
        int d = q >> 5;                // 32 float4 per 128-col row
        int e0 = (q & 31) * 4;
        float md = smui[d], rd = sri[d];
        float cn, df;
        cn = (v.x * invN - md * smuj[e0 + 0]) * rd * srj[e0 + 0];
        df = cn - ((d == e0 + 0) ? 1.f : 0.f); s += df * df;
        cn = (v.y * invN - md * smuj[e0 + 1]) * rd * srj[e0 + 1];
        df = cn - ((d == e0 + 1) ? 1.f : 0.f); s += df * df;
        cn = (v.z * invN - md * smuj[e0 + 2]) * rd * srj[e0 + 2];
        df = cn - ((d == e0 + 2) ? 1.f : 0.f); s += df * df;
        cn = (v.w * invN - md * smuj[e0 + 3]) * rd * srj[e0 + 3];
        df = cn - ((d == e0 + 3) ? 1.f : 0.f); s += df * df;
    }
    for (int o = 32; o; o >>= 1) s += __shfl_down(s, o);
    __shared__ float red[8];
    if ((threadIdx.x & 63) == 0) red[threadIdx.x >> 6] = s;
    __syncthreads();
    if (threadIdx.x == 0) {
        float t = red[0] + red[1] + red[2] + red[3]
                + red[4] + red[5] + red[6] + red[7];
        float x = -15.99f * (G[i * NH + j] - 0.0f);
        float sp = (x > 20.f) ? x : log1pf(expf(x));
        float wgt = 0.929f + (1.f - 0.929f) * sp;
        atomicAdd(out, wgt * t * (1.f / (float)NPAIRS));
    }
}

// ---------------------------------------------------------------- launcher
extern "C" void kernel_launch(void* const* d_in, const int* in_sizes, int n_in,
                              void* d_out, int out_size, void* d_ws, size_t ws_size,
                              hipStream_t stream) {
    const float* X = (const float*)d_in[0];
    const float* G = (const float*)d_in[1];
    float* out = (float*)d_out;
    char* ws = (char*)d_ws;

    float*         sum   = (float*)(ws + SUM_OFF);
    float*         sumsq = (float*)(ws + SUMSQ_OFF);
    float*         pairP = (float*)(ws + PC_OFF);
    unsigned char* Xt    = (unsigned char*)(ws + XT_OFF);

    hipMemsetAsync(ws + SUM_OFF, 0, 16384, stream);                     // sum+sumsq
    hipMemsetAsync(d_out, 0, 4, stream);

    stats_transpose_kernel<<<dim3(16, 256), 256, 0, stream>>>(X, sum, sumsq, Xt);
    gram_kernel<<<dim3(KCHUNKS, NPAIRS), 512, 0, stream>>>(Xt, pairP);
    pair_reduce_kernel<<<NPAIRS, 512, 0, stream>>>(pairP, G, sum, sumsq, out);
}